// Round 6
// baseline (168.258 us; speedup 1.0000x reference)
//
#include <hip/hip_runtime.h>
#include <hip/hip_bf16.h>

// GATConv: N=50000, E=1.6M (row sorted), IN_C=128, HEADS=4, OUT_C=32 (H*C=128)
//   1) prep_kernel:  W -> Wt (bf16, transposed, swizzled)  +  row_ptr boundary scatter
//   2) gemm_kernel:  MFMA bf16 16x16x32, xp = x @ W, fused a_src/a_dst epilogue (r5, verified)
//   3) agg2_kernel:  PERSISTENT bucketed gather. 256 blocks x 1024 thr (co-resident,
//                    1/CU). Wave owns 13 nodes (acc in regs, 2 VGPR/node). Cols
//                    bucket-sorted (col>>13 -> 7 x 2MB xp slices) per node in LDS via
//                    ballot counting-sort; all waves sweep buckets 0..6 together so the
//                    active xp slice is L2-resident. Weights recomputed per edge from
//                    a_dst (bucket-local). Overflow nodes -> direct tail path.

#define IN_C 128
#define HC 128
#define NPB 196      // nodes per block = ceil(50000/256)
#define NPW 13       // nodes per wave  = ceil(196/16)
#define NWAVES 16
#define WCAP 1024    // col-pool entries per wave (expected use ~416)
#define NBKT 7
#define BSH 13       // bucket = col >> 13  (8192 nodes = 2 MB of xp per bucket)

typedef __attribute__((ext_vector_type(8))) __bf16 bfrag_t;
typedef __attribute__((ext_vector_type(4))) float f32x4;
union frag_u { uint4 u; bfrag_t b; };

static __device__ inline unsigned short f2bf(float f) {
    unsigned u = __float_as_uint(f);
    unsigned r = (u + 0x7fffu + ((u >> 16) & 1u)) >> 16;  // round-nearest-even
    return (unsigned short)r;
}
static __device__ inline unsigned pack2(float a, float b) {
    return (unsigned)f2bf(a) | ((unsigned)f2bf(b) << 16);
}
static __device__ inline float bf_lo(unsigned u) { return __uint_as_float(u << 16); }
static __device__ inline float bf_hi(unsigned u) { return __uint_as_float(u & 0xffff0000u); }

// fused: Wt prep (16384 items, first 64 blocks) + row_ptr boundary scatter (E items)
__global__ __launch_bounds__(256) void prep_kernel(const float* __restrict__ W,
                                                   unsigned short* __restrict__ wt,
                                                   const int* __restrict__ row,
                                                   int* __restrict__ row_ptr,
                                                   int n_nodes, int E) {
    int gid = blockIdx.x * 256 + threadIdx.x;
    if (gid < IN_C * HC) {
        int n = gid >> 7, k = gid & 127;
        wt[((size_t)n * 16 + ((k >> 3) ^ (n & 7))) * 8 + (k & 7)] =
            f2bf(W[(size_t)k * HC + n]);
    }
    if (gid < E) {
        int r1 = row[gid];
        int r0 = (gid == 0) ? -1 : row[gid - 1];
        for (int v = r0 + 1; v <= r1; ++v) row_ptr[v] = gid;
        if (gid == E - 1)
            for (int v = r1 + 1; v <= n_nodes; ++v) row_ptr[v] = E;
    }
}

// MFMA GEMM (r5, verified): block = 64 rows x 128 cols, 4 waves.
__global__ __launch_bounds__(256) void gemm_kernel(const float* __restrict__ x,
                                                   const uint4* __restrict__ wt,
                                                   const float* __restrict__ attS,
                                                   const float* __restrict__ attD,
                                                   unsigned short* __restrict__ xp,
                                                   float* __restrict__ a_src,
                                                   float* __restrict__ a_dst, int n_nodes) {
    __shared__ uint4 Bl[2048];
    __shared__ uint4 Al[1024];
    const int tid = threadIdx.x;
    const int base = blockIdx.x * 64;

    #pragma unroll
    for (int i = 0; i < 8; ++i) Bl[tid + 256 * i] = wt[tid + 256 * i];

    #pragma unroll
    for (int i = 0; i < 4; ++i) {
        int idx = tid + 256 * i;
        int row = idx >> 4, chunk = idx & 15;
        uint4 p = make_uint4(0u, 0u, 0u, 0u);
        if (base + row < n_nodes) {
            const float* src = x + (size_t)(base + row) * IN_C + chunk * 8;
            float4 lo = *(const float4*)src;
            float4 hi = *(const float4*)(src + 4);
            p.x = pack2(lo.x, lo.y); p.y = pack2(lo.z, lo.w);
            p.z = pack2(hi.x, hi.y); p.w = pack2(hi.z, hi.w);
        }
        Al[row * 16 + (chunk ^ (row & 7))] = p;
    }
    __syncthreads();

    const int w = tid >> 6, l = tid & 63, l15 = l & 15, q = l >> 4;
    f32x4 acc[8] = {};
    const int arow = 16 * w + l15;
    #pragma unroll
    for (int ks = 0; ks < 4; ++ks) {
        frag_u a; a.u = Al[arow * 16 + ((ks * 4 + q) ^ (arow & 7))];
        #pragma unroll
        for (int t = 0; t < 8; ++t) {
            int brow = 16 * t + l15;
            frag_u b; b.u = Bl[brow * 16 + ((ks * 4 + q) ^ (brow & 7))];
            acc[t] = __builtin_amdgcn_mfma_f32_16x16x32_bf16(a.b, b.b, acc[t], 0, 0, 0);
        }
    }

    float avS[8], avD[8];
    #pragma unroll
    for (int t = 0; t < 8; ++t) {
        avS[t] = attS[16 * t + l15];
        avD[t] = attD[16 * t + l15];
    }
    float hpS[4][4] = {}, hpD[4][4] = {};
    #pragma unroll
    for (int t = 0; t < 8; ++t) {
        #pragma unroll
        for (int r = 0; r < 4; ++r) {
            float v = acc[t][r];
            hpS[r][t >> 1] = fmaf(v, avS[t], hpS[r][t >> 1]);
            hpD[r][t >> 1] = fmaf(v, avD[t], hpD[r][t >> 1]);
            int grow = base + 16 * w + 4 * q + r;
            if (grow < n_nodes)
                xp[(size_t)grow * HC + 16 * t + l15] = f2bf(v);
        }
    }
    #pragma unroll
    for (int r = 0; r < 4; ++r) {
        #pragma unroll
        for (int h = 0; h < 4; ++h) {
            #pragma unroll
            for (int off = 1; off < 16; off <<= 1) {
                hpS[r][h] += __shfl_xor(hpS[r][h], off, 64);
                hpD[r][h] += __shfl_xor(hpD[r][h], off, 64);
            }
        }
        int grow = base + 16 * w + 4 * q + r;
        if (l15 == 0 && grow < n_nodes) {
            *(float4*)(a_src + (size_t)grow * 4) =
                make_float4(hpS[r][0], hpS[r][1], hpS[r][2], hpS[r][3]);
            *(float4*)(a_dst + (size_t)grow * 4) =
                make_float4(hpD[r][0], hpD[r][1], hpD[r][2], hpD[r][3]);
        }
    }
}

// Persistent bucketed aggregation.
__global__ __launch_bounds__(1024) void agg2_kernel(const unsigned* __restrict__ xp,
                                                    const float* __restrict__ a_src,
                                                    const float* __restrict__ a_dst,
                                                    const int* __restrict__ col,
                                                    const int* __restrict__ row_ptr,
                                                    const float* __restrict__ bias,
                                                    float* __restrict__ out, int n_nodes) {
    __shared__ int   pool[NWAVES][WCAP];                       // 64 KB
    __shared__ unsigned short boff[NWAVES][NPW][NBKT + 1];     // 3.3 KB
    __shared__ float asl[NWAVES][NPW][4];                      // 3.3 KB
    __shared__ float invl[NWAVES][NPW][4];                     // 3.3 KB
    __shared__ int   sst[NWAVES][NPW], sdg[NWAVES][NPW];       // 1.7 KB
    __shared__ unsigned smask[NWAVES];

    const int w = threadIdx.x >> 6, lane = threadIdx.x & 63;
    const int h = lane >> 4;  // head of channels (2*lane, 2*lane+1)
    const int bbase = blockIdx.x * NPB;
    const int wlimit = min(bbase + NPB, n_nodes);
    const int base = bbase + w * NPW;
    const unsigned long long below = (1ull << lane) - 1ull;

    if (lane == 0) smask[w] = 0u;

    // ---- stage: per node, compute softmax sums and bucket-sort cols into pool ----
    int pool_used = 0;
    for (int nd = 0; nd < NPW; ++nd) {
        int n = base + nd;
        if (n >= wlimit) continue;
        int st = row_ptr[n], dg = row_ptr[n + 1] - st;
        if (lane == 0) { sst[w][nd] = st; sdg[w][nd] = dg; }

        float4 av = *(const float4*)(a_src + (size_t)n * 4);
        float s0 = 0.f, s1 = 0.f, s2 = 0.f, s3 = 0.f;
        int c0n = 0, c1n = 0, c2n = 0, c3n = 0, c4n = 0, c5n = 0, c6n = 0;
        int nch = (dg + 63) >> 6;

        for (int ch = 0; ch < nch; ++ch) {
            int i = (ch << 6) | lane;
            bool v = i < dg;
            int c = v ? col[st + i] : 0;
            if (v) {
                float4 ad = *(const float4*)(a_dst + (size_t)c * 4);
                float v0 = av.x + ad.x, v1 = av.y + ad.y,
                      v2 = av.z + ad.z, v3 = av.w + ad.w;
                v0 = v0 > 0.f ? v0 : 0.2f * v0;  v1 = v1 > 0.f ? v1 : 0.2f * v1;
                v2 = v2 > 0.f ? v2 : 0.2f * v2;  v3 = v3 > 0.f ? v3 : 0.2f * v3;
                s0 += __expf(v0); s1 += __expf(v1);
                s2 += __expf(v2); s3 += __expf(v3);
            }
            int bkt = c >> BSH;
#define CNT1(BB, CV) { unsigned long long m = __ballot(v && bkt == BB); CV += (int)__popcll(m); }
            CNT1(0, c0n) CNT1(1, c1n) CNT1(2, c2n) CNT1(3, c3n)
            CNT1(4, c4n) CNT1(5, c5n) CNT1(6, c6n)
#undef CNT1
        }
        #pragma unroll
        for (int off = 1; off < 64; off <<= 1) {
            s0 += __shfl_xor(s0, off, 64);
            s1 += __shfl_xor(s1, off, 64);
            s2 += __shfl_xor(s2, off, 64);
            s3 += __shfl_xor(s3, off, 64);
        }
        if (lane == 0) {
            asl[w][nd][0] = av.x;  asl[w][nd][1] = av.y;
            asl[w][nd][2] = av.z;  asl[w][nd][3] = av.w;
            invl[w][nd][0] = 1.0f / (s0 + 1e-8f);
            invl[w][nd][1] = 1.0f / (s1 + 1e-8f);
            invl[w][nd][2] = 1.0f / (s2 + 1e-8f);
            invl[w][nd][3] = 1.0f / (s3 + 1e-8f);
        }

        if (pool_used + dg <= WCAP) {
            if (lane == 0) smask[w] |= (1u << nd);
            int o0 = pool_used, o1 = o0 + c0n, o2 = o1 + c1n, o3 = o2 + c2n;
            int o4 = o3 + c3n, o5 = o4 + c4n, o6 = o5 + c5n, o7 = o6 + c6n;
            if (lane == 0) {
                boff[w][nd][0] = (unsigned short)o0;
                boff[w][nd][1] = (unsigned short)o1;
                boff[w][nd][2] = (unsigned short)o2;
                boff[w][nd][3] = (unsigned short)o3;
                boff[w][nd][4] = (unsigned short)o4;
                boff[w][nd][5] = (unsigned short)o5;
                boff[w][nd][6] = (unsigned short)o6;
                boff[w][nd][7] = (unsigned short)o7;
            }
            int p0 = o0, p1 = o1, p2 = o2, p3 = o3, p4 = o4, p5 = o5, p6 = o6;
            for (int ch = 0; ch < nch; ++ch) {
                int i = (ch << 6) | lane;
                bool v = i < dg;
                int c = v ? col[st + i] : 0;
                int bkt = c >> BSH;
#define PUT1(BB, PV) { unsigned long long m = __ballot(v && bkt == BB); \
                       if (v && bkt == BB) pool[w][PV + (int)__popcll(m & below)] = c; \
                       PV += (int)__popcll(m); }
                PUT1(0, p0) PUT1(1, p1) PUT1(2, p2) PUT1(3, p3)
                PUT1(4, p4) PUT1(5, p5) PUT1(6, p6)
#undef PUT1
            }
            pool_used += dg;
        }
    }

    // ---- bucket sweep: all waves/blocks process bucket b together ----
    float acc0[NPW] = {}, acc1[NPW] = {};
    unsigned sm = smask[w];          // same-wave write, lgkm-ordered

    for (int b = 0; b < NBKT; ++b) {
        #pragma unroll
        for (int nd = 0; nd < NPW; ++nd) {
            if (!(sm & (1u << nd))) continue;
            int j0 = boff[w][nd][b], j1 = boff[w][nd][b + 1];
            float ash = asl[w][nd][h];
            #pragma unroll 2
            for (int j = j0; j < j1; ++j) {
                int c = pool[w][j];
                float ad = a_dst[(size_t)c * 4 + h];
                float vv = ash + ad;
                vv = vv > 0.f ? vv : 0.2f * vv;
                float wt = __expf(vv);
                unsigned u = xp[(size_t)c * 64 + lane];
                acc0[nd] = fmaf(wt, bf_lo(u), acc0[nd]);
                acc1[nd] = fmaf(wt, bf_hi(u), acc1[nd]);
            }
        }
    }

    // ---- tail: unstaged (pool-overflow) nodes, direct path ----
    #pragma unroll
    for (int nd = 0; nd < NPW; ++nd) {
        int n = base + nd;
        if (n >= wlimit || (sm & (1u << nd))) continue;
        int st = sst[w][nd], dg = sdg[w][nd];
        float ash = asl[w][nd][h];
        for (int j = 0; j < dg; ++j) {
            int c = col[st + j];
            float ad = a_dst[(size_t)c * 4 + h];
            float vv = ash + ad;
            vv = vv > 0.f ? vv : 0.2f * vv;
            float wt = __expf(vv);
            unsigned u = xp[(size_t)c * 64 + lane];
            acc0[nd] = fmaf(wt, bf_lo(u), acc0[nd]);
            acc1[nd] = fmaf(wt, bf_hi(u), acc1[nd]);
        }
    }

    // ---- output ----
    float2 bv = *(const float2*)(bias + 2 * lane);
    #pragma unroll
    for (int nd = 0; nd < NPW; ++nd) {
        int n = base + nd;
        if (n >= wlimit) continue;
        float iv = invl[w][nd][h];
        *(float2*)(out + (size_t)n * HC + 2 * lane) =
            make_float2(acc0[nd] * iv + bv.x, acc1[nd] * iv + bv.y);
    }
}

extern "C" void kernel_launch(void* const* d_in, const int* in_sizes, int n_in,
                              void* d_out, int out_size, void* d_ws, size_t ws_size,
                              hipStream_t stream) {
    const float* x       = (const float*)d_in[0];
    const float* weight  = (const float*)d_in[1];
    const float* att_src = (const float*)d_in[2];
    const float* att_dst = (const float*)d_in[3];
    const float* bias    = (const float*)d_in[4];
    const int*   row     = (const int*)d_in[5];
    const int*   col     = (const int*)d_in[6];
    float* out = (float*)d_out;

    const int n_nodes = in_sizes[0] / IN_C;   // 50000
    const int E = in_sizes[5];                // 1.6M

    char* ws = (char*)d_ws;
    unsigned short* xp = (unsigned short*)ws;  ws += (size_t)n_nodes * HC * sizeof(unsigned short);
    float* a_src   = (float*)ws;               ws += (size_t)n_nodes * 4 * sizeof(float);
    float* a_dst   = (float*)ws;               ws += (size_t)n_nodes * 4 * sizeof(float);
    unsigned short* wt = (unsigned short*)ws;  ws += (size_t)IN_C * HC * sizeof(unsigned short);
    int*   row_ptr = (int*)ws;                 ws += (size_t)(n_nodes + 1) * sizeof(int);

    prep_kernel<<<(E + 255) / 256, 256, 0, stream>>>(weight, wt, row, row_ptr, n_nodes, E);
    gemm_kernel<<<(n_nodes + 63) / 64, 256, 0, stream>>>(x, (const uint4*)wt,
                                                         att_src, att_dst,
                                                         xp, a_src, a_dst, n_nodes);
    agg2_kernel<<<(n_nodes + NPB - 1) / NPB, 1024, 0, stream>>>((const unsigned*)xp,
                                                                a_src, a_dst, col, row_ptr,
                                                                bias, out, n_nodes);
}

// Round 7
// 118.400 us; speedup vs baseline: 1.4211x; 1.4211x over previous
//
#include <hip/hip_runtime.h>
#include <hip/hip_bf16.h>

// GATConv: N=50000, E=1.6M (row sorted), IN_C=128, HEADS=4, OUT_C=32 (H*C=128)
//   1) prep_kernel:  W -> Wt (bf16, transposed, swizzled)  +  row_ptr boundary scatter
//   2) gemm_kernel:  MFMA bf16 16x16x32, xp = x @ W, fused a_src/a_dst epilogue
//   3) agg3_kernel:  persistent bucketed gather, weights PRECOMPUTED into LDS pool.
//                    768 blocks x 512 thr (3/CU co-resident, 24 waves/CU). Wave owns
//                    ~8 nodes; stage = count cols per bucket (ballot), then one exp
//                    pass writing (col, w0..w3 as 2xbf16pair) bucket-sorted into LDS.
//                    Sweep (bucket 0..6, __syncthreads-locked): pure gather
//                    LDS(col,w) -> xp load -> fma, unroll 4. Traffic win of r6
//                    (FETCH 173->65MB) + MLP of r5.

#define IN_C 128
#define HC 128
#define NPB 66       // nodes per block (768 * 66 >= 50000)
#define NPW 9        // max nodes per wave (ceil(66/8))
#define AGG_WAVES 8
#define WCAP 416     // pooled edges per wave (mean ~264)
#define NBKT 7
#define BSH 13       // bucket = col >> 13 (2MB xp slice per bucket)

typedef __attribute__((ext_vector_type(8))) __bf16 bfrag_t;
typedef __attribute__((ext_vector_type(4))) float f32x4;
union frag_u { uint4 u; bfrag_t b; };

static __device__ inline unsigned short f2bf(float f) {
    unsigned u = __float_as_uint(f);
    unsigned r = (u + 0x7fffu + ((u >> 16) & 1u)) >> 16;  // round-nearest-even
    return (unsigned short)r;
}
static __device__ inline unsigned pack2(float a, float b) {
    return (unsigned)f2bf(a) | ((unsigned)f2bf(b) << 16);
}
static __device__ inline float bf_lo(unsigned u) { return __uint_as_float(u << 16); }
static __device__ inline float bf_hi(unsigned u) { return __uint_as_float(u & 0xffff0000u); }

__global__ __launch_bounds__(256) void prep_kernel(const float* __restrict__ W,
                                                   unsigned short* __restrict__ wt,
                                                   const int* __restrict__ row,
                                                   int* __restrict__ row_ptr,
                                                   int n_nodes, int E) {
    int gid = blockIdx.x * 256 + threadIdx.x;
    if (gid < IN_C * HC) {
        int n = gid >> 7, k = gid & 127;
        wt[((size_t)n * 16 + ((k >> 3) ^ (n & 7))) * 8 + (k & 7)] =
            f2bf(W[(size_t)k * HC + n]);
    }
    if (gid < E) {
        int r1 = row[gid];
        int r0 = (gid == 0) ? -1 : row[gid - 1];
        for (int v = r0 + 1; v <= r1; ++v) row_ptr[v] = gid;
        if (gid == E - 1)
            for (int v = r1 + 1; v <= n_nodes; ++v) row_ptr[v] = E;
    }
}

// MFMA GEMM (r5, verified): block = 64 rows x 128 cols, 4 waves.
__global__ __launch_bounds__(256) void gemm_kernel(const float* __restrict__ x,
                                                   const uint4* __restrict__ wt,
                                                   const float* __restrict__ attS,
                                                   const float* __restrict__ attD,
                                                   unsigned short* __restrict__ xp,
                                                   float* __restrict__ a_src,
                                                   float* __restrict__ a_dst, int n_nodes) {
    __shared__ uint4 Bl[2048];
    __shared__ uint4 Al[1024];
    const int tid = threadIdx.x;
    const int base = blockIdx.x * 64;

    #pragma unroll
    for (int i = 0; i < 8; ++i) Bl[tid + 256 * i] = wt[tid + 256 * i];

    #pragma unroll
    for (int i = 0; i < 4; ++i) {
        int idx = tid + 256 * i;
        int row = idx >> 4, chunk = idx & 15;
        uint4 p = make_uint4(0u, 0u, 0u, 0u);
        if (base + row < n_nodes) {
            const float* src = x + (size_t)(base + row) * IN_C + chunk * 8;
            float4 lo = *(const float4*)src;
            float4 hi = *(const float4*)(src + 4);
            p.x = pack2(lo.x, lo.y); p.y = pack2(lo.z, lo.w);
            p.z = pack2(hi.x, hi.y); p.w = pack2(hi.z, hi.w);
        }
        Al[row * 16 + (chunk ^ (row & 7))] = p;
    }
    __syncthreads();

    const int w = tid >> 6, l = tid & 63, l15 = l & 15, q = l >> 4;
    f32x4 acc[8] = {};
    const int arow = 16 * w + l15;
    #pragma unroll
    for (int ks = 0; ks < 4; ++ks) {
        frag_u a; a.u = Al[arow * 16 + ((ks * 4 + q) ^ (arow & 7))];
        #pragma unroll
        for (int t = 0; t < 8; ++t) {
            int brow = 16 * t + l15;
            frag_u b; b.u = Bl[brow * 16 + ((ks * 4 + q) ^ (brow & 7))];
            acc[t] = __builtin_amdgcn_mfma_f32_16x16x32_bf16(a.b, b.b, acc[t], 0, 0, 0);
        }
    }

    float avS[8], avD[8];
    #pragma unroll
    for (int t = 0; t < 8; ++t) {
        avS[t] = attS[16 * t + l15];
        avD[t] = attD[16 * t + l15];
    }
    float hpS[4][4] = {}, hpD[4][4] = {};
    #pragma unroll
    for (int t = 0; t < 8; ++t) {
        #pragma unroll
        for (int r = 0; r < 4; ++r) {
            float v = acc[t][r];
            hpS[r][t >> 1] = fmaf(v, avS[t], hpS[r][t >> 1]);
            hpD[r][t >> 1] = fmaf(v, avD[t], hpD[r][t >> 1]);
            int grow = base + 16 * w + 4 * q + r;
            if (grow < n_nodes)
                xp[(size_t)grow * HC + 16 * t + l15] = f2bf(v);
        }
    }
    #pragma unroll
    for (int r = 0; r < 4; ++r) {
        #pragma unroll
        for (int h = 0; h < 4; ++h) {
            #pragma unroll
            for (int off = 1; off < 16; off <<= 1) {
                hpS[r][h] += __shfl_xor(hpS[r][h], off, 64);
                hpD[r][h] += __shfl_xor(hpD[r][h], off, 64);
            }
        }
        int grow = base + 16 * w + 4 * q + r;
        if (l15 == 0 && grow < n_nodes) {
            *(float4*)(a_src + (size_t)grow * 4) =
                make_float4(hpS[r][0], hpS[r][1], hpS[r][2], hpS[r][3]);
            *(float4*)(a_dst + (size_t)grow * 4) =
                make_float4(hpD[r][0], hpD[r][1], hpD[r][2], hpD[r][3]);
        }
    }
}

// Persistent bucketed aggregation, weights precomputed in pool.
__global__ __launch_bounds__(512, 6) void agg3_kernel(const unsigned* __restrict__ xp,
                                                      const float* __restrict__ a_src,
                                                      const float* __restrict__ a_dst,
                                                      const int* __restrict__ col,
                                                      const int* __restrict__ row_ptr,
                                                      const float* __restrict__ bias,
                                                      float* __restrict__ out, int n_nodes) {
    __shared__ int      pool_c[AGG_WAVES][WCAP];            // 13 KB
    __shared__ unsigned pool_w[AGG_WAVES][WCAP * 2];        // 26 KB (w0w1, w2w3 bf16 pairs)
    __shared__ unsigned short boff[AGG_WAVES][NPW][NBKT + 1];
    __shared__ float    invl[AGG_WAVES][NPW][4];

    const int w = threadIdx.x >> 6, lane = threadIdx.x & 63;
    const int h = lane >> 4;                 // head of channels (2*lane, 2*lane+1)
    const int bbase = blockIdx.x * NPB;
    const int wlimit = min(bbase + NPB, n_nodes);
    const unsigned long long below = (1ull << lane) - 1ull;

    // ---- stage ----
    unsigned sm = 0;          // staged-node mask (computed uniformly by all lanes)
    int pool_used = 0;
    for (int nd = 0; nd < NPW; ++nd) {
        int n = bbase + nd * 8 + w;
        if (n >= wlimit) continue;
        int st = row_ptr[n], dg = row_ptr[n + 1] - st;
        if (pool_used + dg > WCAP) continue;      // unstaged -> tail path
        sm |= (1u << nd);
        int nch = (dg + 63) >> 6;

        // pass 1: bucket counts (ballot)
        int c0n = 0, c1n = 0, c2n = 0, c3n = 0, c4n = 0, c5n = 0, c6n = 0;
        for (int ch = 0; ch < nch; ++ch) {
            int i = (ch << 6) | lane;
            bool v = i < dg;
            int c = v ? col[st + i] : 0;
            int bkt = c >> BSH;
#define CNT1(BB, CV) { unsigned long long m = __ballot(v && bkt == BB); CV += (int)__popcll(m); }
            CNT1(0, c0n) CNT1(1, c1n) CNT1(2, c2n) CNT1(3, c3n)
            CNT1(4, c4n) CNT1(5, c5n) CNT1(6, c6n)
#undef CNT1
        }
        int o0 = pool_used, o1 = o0 + c0n, o2 = o1 + c1n, o3 = o2 + c2n;
        int o4 = o3 + c3n, o5 = o4 + c4n, o6 = o5 + c5n, o7 = o6 + c6n;
        if (lane == 0) {
            boff[w][nd][0] = (unsigned short)o0;  boff[w][nd][1] = (unsigned short)o1;
            boff[w][nd][2] = (unsigned short)o2;  boff[w][nd][3] = (unsigned short)o3;
            boff[w][nd][4] = (unsigned short)o4;  boff[w][nd][5] = (unsigned short)o5;
            boff[w][nd][6] = (unsigned short)o6;  boff[w][nd][7] = (unsigned short)o7;
        }

        // pass 2: exp once, scatter (col, weights) into pool, accumulate sums
        float4 av = *(const float4*)(a_src + (size_t)n * 4);
        float s0 = 0.f, s1 = 0.f, s2 = 0.f, s3 = 0.f;
        int p0 = o0, p1 = o1, p2 = o2, p3 = o3, p4 = o4, p5 = o5, p6 = o6;
        for (int ch = 0; ch < nch; ++ch) {
            int i = (ch << 6) | lane;
            bool v = i < dg;
            int c = v ? col[st + i] : 0;
            float4 ad = make_float4(0.f, 0.f, 0.f, 0.f);
            if (v) ad = *(const float4*)(a_dst + (size_t)c * 4);
            float v0 = av.x + ad.x, v1 = av.y + ad.y, v2 = av.z + ad.z, v3 = av.w + ad.w;
            v0 = v0 > 0.f ? v0 : 0.2f * v0;  v1 = v1 > 0.f ? v1 : 0.2f * v1;
            v2 = v2 > 0.f ? v2 : 0.2f * v2;  v3 = v3 > 0.f ? v3 : 0.2f * v3;
            float w0 = v ? __expf(v0) : 0.f, w1 = v ? __expf(v1) : 0.f;
            float w2 = v ? __expf(v2) : 0.f, w3 = v ? __expf(v3) : 0.f;
            s0 += w0; s1 += w1; s2 += w2; s3 += w3;
            unsigned u01 = pack2(w0, w1), u23 = pack2(w2, w3);
            int bkt = c >> BSH;
#define PUT1(BB, PV) { unsigned long long m = __ballot(v && bkt == BB);          \
                       if (v && bkt == BB) {                                      \
                           int pos = PV + (int)__popcll(m & below);               \
                           pool_c[w][pos] = c;                                    \
                           pool_w[w][2 * pos] = u01; pool_w[w][2 * pos + 1] = u23;\
                       }                                                          \
                       PV += (int)__popcll(m); }
            PUT1(0, p0) PUT1(1, p1) PUT1(2, p2) PUT1(3, p3)
            PUT1(4, p4) PUT1(5, p5) PUT1(6, p6)
#undef PUT1
        }
        #pragma unroll
        for (int off = 1; off < 64; off <<= 1) {
            s0 += __shfl_xor(s0, off, 64);
            s1 += __shfl_xor(s1, off, 64);
            s2 += __shfl_xor(s2, off, 64);
            s3 += __shfl_xor(s3, off, 64);
        }
        float shh = h == 0 ? s0 : h == 1 ? s1 : h == 2 ? s2 : s3;
        if ((lane & 15) == 0) invl[w][nd][h] = 1.0f / (shh + 1e-8f);
        pool_used = o7;
    }

    // ---- bucket sweep (phase-locked across the block's waves) ----
    float acc0[NPW] = {}, acc1[NPW] = {};
    for (int b = 0; b < NBKT; ++b) {
        __syncthreads();
        #pragma unroll
        for (int nd = 0; nd < NPW; ++nd) {
            if (!(sm & (1u << nd))) continue;
            int j0 = boff[w][nd][b], j1 = boff[w][nd][b + 1];
            int j = j0;
            for (; j + 4 <= j1; j += 4) {
                int c0 = pool_c[w][j],     c1 = pool_c[w][j + 1];
                int c2 = pool_c[w][j + 2], c3 = pool_c[w][j + 3];
                uint2 q0 = *(const uint2*)&pool_w[w][2 * j];
                uint2 q1 = *(const uint2*)&pool_w[w][2 * (j + 1)];
                uint2 q2 = *(const uint2*)&pool_w[w][2 * (j + 2)];
                uint2 q3 = *(const uint2*)&pool_w[w][2 * (j + 3)];
                unsigned u0 = xp[(size_t)c0 * 64 + lane];
                unsigned u1 = xp[(size_t)c1 * 64 + lane];
                unsigned u2 = xp[(size_t)c2 * 64 + lane];
                unsigned u3 = xp[(size_t)c3 * 64 + lane];
                unsigned uw0 = (h & 2) ? q0.y : q0.x;
                unsigned uw1 = (h & 2) ? q1.y : q1.x;
                unsigned uw2 = (h & 2) ? q2.y : q2.x;
                unsigned uw3 = (h & 2) ? q3.y : q3.x;
                float w0 = (h & 1) ? bf_hi(uw0) : bf_lo(uw0);
                float w1 = (h & 1) ? bf_hi(uw1) : bf_lo(uw1);
                float w2 = (h & 1) ? bf_hi(uw2) : bf_lo(uw2);
                float w3 = (h & 1) ? bf_hi(uw3) : bf_lo(uw3);
                acc0[nd] = fmaf(w0, bf_lo(u0), acc0[nd]);
                acc1[nd] = fmaf(w0, bf_hi(u0), acc1[nd]);
                acc0[nd] = fmaf(w1, bf_lo(u1), acc0[nd]);
                acc1[nd] = fmaf(w1, bf_hi(u1), acc1[nd]);
                acc0[nd] = fmaf(w2, bf_lo(u2), acc0[nd]);
                acc1[nd] = fmaf(w2, bf_hi(u2), acc1[nd]);
                acc0[nd] = fmaf(w3, bf_lo(u3), acc0[nd]);
                acc1[nd] = fmaf(w3, bf_hi(u3), acc1[nd]);
            }
            for (; j < j1; ++j) {
                int c0 = pool_c[w][j];
                uint2 q0 = *(const uint2*)&pool_w[w][2 * j];
                unsigned u0 = xp[(size_t)c0 * 64 + lane];
                unsigned uw0 = (h & 2) ? q0.y : q0.x;
                float w0 = (h & 1) ? bf_hi(uw0) : bf_lo(uw0);
                acc0[nd] = fmaf(w0, bf_lo(u0), acc0[nd]);
                acc1[nd] = fmaf(w0, bf_hi(u0), acc1[nd]);
            }
        }
    }

    // ---- tail: unstaged (overflow) nodes, direct path ----
    #pragma unroll
    for (int nd = 0; nd < NPW; ++nd) {
        int n = bbase + nd * 8 + w;
        if (n >= wlimit || (sm & (1u << nd))) continue;
        int st = row_ptr[n], dg = row_ptr[n + 1] - st;
        float ash = a_src[(size_t)n * 4 + h];
        float s = 0.f;
        for (int j = 0; j < dg; ++j) {
            int c = col[st + j];
            float ad = a_dst[(size_t)c * 4 + h];
            float vv = ash + ad;
            vv = vv > 0.f ? vv : 0.2f * vv;
            float wt = __expf(vv);
            s += wt;
            unsigned u = xp[(size_t)c * 64 + lane];
            acc0[nd] = fmaf(wt, bf_lo(u), acc0[nd]);
            acc1[nd] = fmaf(wt, bf_hi(u), acc1[nd]);
        }
        if ((lane & 15) == 0) invl[w][nd][h] = 1.0f / (s + 1e-8f);
    }

    // ---- output ----
    float2 bv = *(const float2*)(bias + 2 * lane);
    #pragma unroll
    for (int nd = 0; nd < NPW; ++nd) {
        int n = bbase + nd * 8 + w;
        if (n >= wlimit) continue;
        float iv = invl[w][nd][h];
        *(float2*)(out + (size_t)n * HC + 2 * lane) =
            make_float2(acc0[nd] * iv + bv.x, acc1[nd] * iv + bv.y);
    }
}

extern "C" void kernel_launch(void* const* d_in, const int* in_sizes, int n_in,
                              void* d_out, int out_size, void* d_ws, size_t ws_size,
                              hipStream_t stream) {
    const float* x       = (const float*)d_in[0];
    const float* weight  = (const float*)d_in[1];
    const float* att_src = (const float*)d_in[2];
    const float* att_dst = (const float*)d_in[3];
    const float* bias    = (const float*)d_in[4];
    const int*   row     = (const int*)d_in[5];
    const int*   col     = (const int*)d_in[6];
    float* out = (float*)d_out;

    const int n_nodes = in_sizes[0] / IN_C;   // 50000
    const int E = in_sizes[5];                // 1.6M

    char* ws = (char*)d_ws;
    unsigned short* xp = (unsigned short*)ws;  ws += (size_t)n_nodes * HC * sizeof(unsigned short);
    float* a_src   = (float*)ws;               ws += (size_t)n_nodes * 4 * sizeof(float);
    float* a_dst   = (float*)ws;               ws += (size_t)n_nodes * 4 * sizeof(float);
    unsigned short* wt = (unsigned short*)ws;  ws += (size_t)IN_C * HC * sizeof(unsigned short);
    int*   row_ptr = (int*)ws;                 ws += (size_t)(n_nodes + 1) * sizeof(int);

    prep_kernel<<<(E + 255) / 256, 256, 0, stream>>>(weight, wt, row, row_ptr, n_nodes, E);
    gemm_kernel<<<(n_nodes + 63) / 64, 256, 0, stream>>>(x, (const uint4*)wt,
                                                         att_src, att_dst,
                                                         xp, a_src, a_dst, n_nodes);
    const int agg_grid = (n_nodes + NPB - 1) / NPB;   // 758 <= 768 (3/CU co-resident)
    agg3_kernel<<<agg_grid, 512, 0, stream>>>((const unsigned*)xp, a_src, a_dst,
                                              col, row_ptr, bias, out, n_nodes);
}